// Round 1
// baseline (1813.530 us; speedup 1.0000x reference)
//
#include <hip/hip_runtime.h>
#include <hip/hip_fp16.h>

typedef _Float16 f16;
typedef _Float16 f16x2 __attribute__((ext_vector_type(2)));
typedef _Float16 f16x4 __attribute__((ext_vector_type(4)));
typedef _Float16 f16x8 __attribute__((ext_vector_type(8)));
typedef float    f32x4 __attribute__((ext_vector_type(4)));

// Problem constants
// B=64, S=32, P=49, F=2048, E=512, H=512, V=32000

static __device__ __forceinline__ float fdot2f(f16x2 a, f16x2 b, float c) {
#if __has_builtin(__builtin_amdgcn_fdot2)
  return __builtin_amdgcn_fdot2(a, b, c, false);
#else
  return c + (float)a.x * (float)b.x + (float)a.y * (float)b.y;
#endif
}

// ---------------- f32 -> f16 convert (vectorized) ----------------
__global__ void k_cvt(const float* __restrict__ in, f16* __restrict__ out, long n4) {
  long i = (long)blockIdx.x * blockDim.x + threadIdx.x;
  long stride = (long)gridDim.x * blockDim.x;
  for (; i < n4; i += stride) {
    float4 v = ((const float4*)in)[i];
    f16x4 o;
    o.x = (f16)v.x; o.y = (f16)v.y; o.z = (f16)v.z; o.w = (f16)v.w;
    ((f16x4*)out)[i] = o;
  }
}

// ---------------- embedding gather -> f16 A matrix (n = b*32+s) ----------------
__global__ void k_embed(const int* __restrict__ caps, const float* __restrict__ table,
                        f16* __restrict__ out) {
  int n = blockIdx.x;                 // 0..2047
  int tok = caps[n];
  const float* src = table + (long)tok * 512;
  f16* dst = out + (long)n * 512;
  for (int e = threadIdx.x; e < 512; e += 256) dst[e] = (f16)src[e];
}

// ---------------- pack U_a: UaPK[k2*512 + j] = (U_a[j,2k2], U_a[j,2k2+1]) ----------------
__global__ void k_pack_ua(const float* __restrict__ U, f16x2* __restrict__ out) {
  int idx = blockIdx.x * 256 + threadIdx.x;     // 131072 total
  int k2 = idx >> 9, j = idx & 511;
  f16x2 v; v.x = (f16)U[(long)j * 512 + 2 * k2]; v.y = (f16)U[(long)j * 512 + 2 * k2 + 1];
  out[idx] = v;  // idx == k2*512 + j
}

// ---------------- pack W_hh: out[(k2*512+j)*4+g] = (W_hh[g*512+j,2k2], W_hh[g*512+j,2k2+1]) ----
__global__ void k_pack_whh(const float* __restrict__ W, f16x2* __restrict__ out) {
  long idx = (long)blockIdx.x * 256 + threadIdx.x;   // 524288 total
  int g = idx & 3; int j = (idx >> 2) & 511; int k2 = idx >> 11;
  long row = g * 512 + j;
  f16x2 v; v.x = (f16)W[row * 512 + 2 * k2]; v.y = (f16)W[row * 512 + 2 * k2 + 1];
  out[idx] = v;
}

// ---------------- mean features -> h0,c0 (fp32 direct) ----------------
__global__ __launch_bounds__(512) void k_h0c0(const float* __restrict__ feat,
                                              const float* __restrict__ Wh, const float* __restrict__ bh,
                                              const float* __restrict__ Wc, const float* __restrict__ bc,
                                              float* __restrict__ h0, float* __restrict__ c0) {
  __shared__ float mf[2048];
  int b = blockIdx.x, tid = threadIdx.x;
  for (int e = tid; e < 2048; e += 512) {
    float s = 0.f;
    for (int p = 0; p < 49; ++p) s += feat[((long)(b * 49 + p)) * 2048 + e];
    mf[e] = s * (1.f / 49.f);
  }
  __syncthreads();
  int j = tid;
  float ah = bh[j], ac = bc[j];
  const float4* whr = (const float4*)(Wh + (long)j * 2048);
  const float4* wcr = (const float4*)(Wc + (long)j * 2048);
  for (int e4 = 0; e4 < 512; ++e4) {
    float4 m4 = *(const float4*)&mf[e4 * 4];
    float4 a = whr[e4], cc = wcr[e4];
    ah += m4.x * a.x + m4.y * a.y + m4.z * a.z + m4.w * a.w;
    ac += m4.x * cc.x + m4.y * cc.y + m4.z * cc.z + m4.w * cc.w;
  }
  h0[(long)b * 512 + j] = ah;
  c0[(long)b * 512 + j] = ac;
}

// ---------------- generic f16 MFMA GEMM: C[M,N] = A[M,K] @ W[N,K]^T + bias ----------------
// mode 0: f32 out @ ldc ; mode 1: f16 out @ ldc ; mode 2: f16 out g-interleaved (featW4)
__global__ __launch_bounds__(256) void k_gemm(const f16* __restrict__ A, long lda,
                                              const f16* __restrict__ Bw, long ldb,
                                              const float* __restrict__ bias1,
                                              const float* __restrict__ bias2,
                                              void* __restrict__ Cout, long ldc,
                                              int K, int mode) {
  __shared__ f16 As[64][40];   // +8 pad: bank-conflict-friendly b128 reads
  __shared__ f16 Bs[64][40];
  const int tid = threadIdx.x;
  const int lane = tid & 63, wave = tid >> 6;
  const long m0 = (long)blockIdx.y * 64, n0 = (long)blockIdx.x * 64;
  const int lr = tid >> 2, lc = (tid & 3) * 8;
  const int wr = (wave >> 1) * 32, wc = (wave & 1) * 32;
  f32x4 acc[2][2] = {};
  const f16* Ap = A + (m0 + lr) * lda + lc;
  const f16* Bp = Bw + (n0 + lr) * ldb + lc;
  for (int k0 = 0; k0 < K; k0 += 32) {
    uint4 av = *(const uint4*)(Ap + k0);
    uint4 bv = *(const uint4*)(Bp + k0);
    __syncthreads();
    *(uint4*)&As[lr][lc] = av;
    *(uint4*)&Bs[lr][lc] = bv;
    __syncthreads();
#pragma unroll
    for (int mi = 0; mi < 2; ++mi) {
      f16x8 af = *(const f16x8*)&As[wr + mi * 16 + (lane & 15)][(lane >> 4) * 8];
#pragma unroll
      for (int ni = 0; ni < 2; ++ni) {
        f16x8 bf = *(const f16x8*)&Bs[wc + ni * 16 + (lane & 15)][(lane >> 4) * 8];
        acc[mi][ni] = __builtin_amdgcn_mfma_f32_16x16x32_f16(af, bf, acc[mi][ni], 0, 0, 0);
      }
    }
  }
#pragma unroll
  for (int mi = 0; mi < 2; ++mi)
#pragma unroll
    for (int ni = 0; ni < 2; ++ni) {
      int row_b = wr + mi * 16 + (lane >> 4) * 4;
      long gcol = n0 + wc + ni * 16 + (lane & 15);
      float badd = (bias1 ? bias1[gcol] : 0.f) + (bias2 ? bias2[gcol] : 0.f);
#pragma unroll
      for (int r = 0; r < 4; ++r) {
        long grow = m0 + row_b + r;
        float v = acc[mi][ni][r] + badd;
        if (mode == 0)      ((float*)Cout)[grow * ldc + gcol] = v;
        else if (mode == 1) ((f16*)Cout)[grow * ldc + gcol] = (f16)v;
        else                ((f16*)Cout)[grow * 2048 + ((gcol & 511) << 2) + (gcol >> 9)] = (f16)v;
      }
    }
}

// ---------------- persistent sequential decoder: one block per batch element ----------------
__global__ __launch_bounds__(512) void k_seq(const f16* __restrict__ UaPK, const float* __restrict__ b_Ua,
                                             const f16* __restrict__ att1, const float* __restrict__ va,
                                             const f16* __restrict__ featW4, const float* __restrict__ gates_x,
                                             const f16* __restrict__ Whh4, const float* __restrict__ h0,
                                             const float* __restrict__ c0, f16* __restrict__ Hbuf,
                                             float* __restrict__ attw_out) {
  __shared__ __align__(16) f16 hh[512];
  __shared__ float att2[512];
  __shared__ float sc[64];
  __shared__ float wl[49];
  const int b = blockIdx.x, tid = threadIdx.x;
  const int lane = tid & 63, wave = tid >> 6;
  float c = c0[(long)b * 512 + tid];
  const float bua = b_Ua[tid];
  hh[tid] = (f16)h0[(long)b * 512 + tid];
  __syncthreads();

  const f16x2* hp = (const f16x2*)hh;
  const uint4* W4 = (const uint4*)Whh4;
  const f16* fwbase = featW4 + (long)b * 49 * 2048 + tid * 4;

  for (int t = 0; t < 32; ++t) {
    const long n = (long)b * 32 + t;
    // (1) att2 = h @ U_a^T + b_Ua
    float a2 = bua;
#pragma unroll 4
    for (int k2 = 0; k2 < 256; ++k2)
      a2 = fdot2f(hp[k2], ((const f16x2*)UaPK)[k2 * 512 + tid], a2);
    att2[tid] = a2;
    __syncthreads();
    // (2) scores: wave w handles p = w, w+8, ...
    for (int p = wave; p < 49; p += 8) {
      const f16* arow = att1 + ((long)b * 49 + p) * 512;
      float s = 0.f;
#pragma unroll
      for (int kk = 0; kk < 8; ++kk) {
        int k = lane + kk * 64;
        float x = (float)arow[k] + att2[k];
        float e = __expf(2.f * x);
        float th = 1.f - 2.f / (e + 1.f);
        s += va[k] * th;
      }
#pragma unroll
      for (int off = 32; off; off >>= 1) s += __shfl_xor(s, off);
      if (lane == 0) sc[p] = s;
    }
    __syncthreads();
    // (3) softmax over P=49 by wave 0 (b_va is a constant shift -> softmax-invariant)
    if (wave == 0) {
      float s = (lane < 49) ? sc[lane] : -1e30f;
      float m = s;
#pragma unroll
      for (int off = 32; off; off >>= 1) m = fmaxf(m, __shfl_xor(m, off));
      float e = (lane < 49) ? __expf(s - m) : 0.f;
      float sum = e;
#pragma unroll
      for (int off = 32; off; off >>= 1) sum += __shfl_xor(sum, off);
      float wv = e / sum;
      if (lane < 49) { wl[lane] = wv; attw_out[n * 49 + lane] = wv; }
    }
    __syncthreads();
    // (4) gates: col set {tid, 512+tid, 1024+tid, 1536+tid} = (i,f,g,o)[tid]
    const float* gx = gates_x + n * 2048;
    float g0 = gx[tid], g1 = gx[512 + tid], g2 = gx[1024 + tid], g3 = gx[1536 + tid];
    // context part: sum_p w[p] * featW[b,p,col]
    for (int p = 0; p < 49; ++p) {
      float wp = wl[p];
      uint2 u = *(const uint2*)(fwbase + (long)p * 2048);
      f16x2 aa = __builtin_bit_cast(f16x2, u.x);
      f16x2 bb = __builtin_bit_cast(f16x2, u.y);
      g0 += wp * (float)aa.x; g1 += wp * (float)aa.y;
      g2 += wp * (float)bb.x; g3 += wp * (float)bb.y;
    }
    // recurrent part: sum_k h[k] * W_hh[col,k]
#pragma unroll 2
    for (int k2 = 0; k2 < 256; ++k2) {
      f16x2 hv = hp[k2];
      uint4 wv4 = W4[k2 * 512 + tid];
      g0 = fdot2f(hv, __builtin_bit_cast(f16x2, wv4.x), g0);
      g1 = fdot2f(hv, __builtin_bit_cast(f16x2, wv4.y), g1);
      g2 = fdot2f(hv, __builtin_bit_cast(f16x2, wv4.z), g2);
      g3 = fdot2f(hv, __builtin_bit_cast(f16x2, wv4.w), g3);
    }
    // LSTM pointwise
    float iv = 1.f / (1.f + __expf(-g0));
    float fv = 1.f / (1.f + __expf(-g1));
    float e2 = __expf(2.f * g2); float gv = 1.f - 2.f / (e2 + 1.f);
    float ov = 1.f / (1.f + __expf(-g3));
    c = fv * c + iv * gv;
    float e3 = __expf(2.f * c); float tc = 1.f - 2.f / (e3 + 1.f);
    float hn = ov * tc;
    __syncthreads();            // all reads of hh done
    hh[tid] = (f16)hn;
    Hbuf[n * 512 + tid] = (f16)hn;
    __syncthreads();            // hh ready for next step
  }
}

extern "C" void kernel_launch(void* const* d_in, const int* in_sizes, int n_in,
                              void* d_out, int out_size, void* d_ws, size_t ws_size,
                              hipStream_t stream) {
  const int*   caps = (const int*)d_in[0];
  const float* feat = (const float*)d_in[1];
  const float* etab = (const float*)d_in[2];
  const float* W_a  = (const float*)d_in[3];
  const float* b_Wa = (const float*)d_in[4];
  const float* U_a  = (const float*)d_in[5];
  const float* b_Ua = (const float*)d_in[6];
  const float* v_a  = (const float*)d_in[7];
  /* d_in[8] b_va: softmax-invariant, unused */
  const float* W_ih = (const float*)d_in[9];
  const float* b_ih = (const float*)d_in[10];
  const float* W_hh = (const float*)d_in[11];
  const float* b_hh = (const float*)d_in[12];
  const float* fc_W = (const float*)d_in[13];
  const float* fc_b = (const float*)d_in[14];
  const float* Wh   = (const float*)d_in[15];
  const float* bh   = (const float*)d_in[16];
  const float* Wc   = (const float*)d_in[17];
  const float* bc   = (const float*)d_in[18];

  char* ws = (char*)d_ws;
  size_t off = 0;
  auto alloc = [&](size_t bytes) { void* p = ws + off; off += (bytes + 255) & ~(size_t)255; return p; };
  f16* feat_h  = (f16*)alloc(6422528ull * 2);   // B*P*F
  f16* W_a_h   = (f16*)alloc(1048576ull * 2);   // H*F
  f16* W_ih_h  = (f16*)alloc(5242880ull * 2);   // 4H*(E+F)
  f16* fc_W_h  = (f16*)alloc(16384000ull * 2);  // V*H
  f16* Aemb    = (f16*)alloc(1048576ull * 2);   // B*S*E
  f16* UaPK    = (f16*)alloc(262144ull * 2);    // H*H packed
  f16* Whh4    = (f16*)alloc(1048576ull * 2);   // 4H*H packed
  f16* att1_h  = (f16*)alloc(1605632ull * 2);   // B*P*H
  f16* featW4  = (f16*)alloc(6422528ull * 2);   // B*P*4H interleaved
  float* gates_x = (float*)alloc(4194304ull * 4); // B*S*4H
  float* h0    = (float*)alloc(32768ull * 4);
  float* c0    = (float*)alloc(32768ull * 4);
  f16* Hbuf    = (f16*)alloc(1048576ull * 2);   // B*S*H
  (void)ws_size; (void)in_sizes; (void)n_in; (void)out_size;

  float* out_logits = (float*)d_out;
  float* out_attw   = out_logits + 65536000ull;

  // Phase A: converts / packs / precompute
  k_cvt<<<2048, 256, 0, stream>>>(feat, feat_h, 6422528 / 4);
  k_cvt<<<1024, 256, 0, stream>>>(W_a, W_a_h, 1048576 / 4);
  k_cvt<<<2048, 256, 0, stream>>>(W_ih, W_ih_h, 5242880 / 4);
  k_cvt<<<4096, 256, 0, stream>>>(fc_W, fc_W_h, 16384000 / 4);
  k_embed<<<2048, 256, 0, stream>>>(caps, etab, Aemb);
  k_pack_ua<<<512, 256, 0, stream>>>(U_a, (f16x2*)UaPK);
  k_pack_whh<<<2048, 256, 0, stream>>>(W_hh, (f16x2*)Whh4);
  k_h0c0<<<64, 512, 0, stream>>>(feat, Wh, bh, Wc, bc, h0, c0);

  dim3 blk(256);
  // att1 = features @ W_a^T + b_Wa         [3136,512]  K=2048 -> f16
  k_gemm<<<dim3(512 / 64, 3136 / 64), blk, 0, stream>>>(feat_h, 2048, W_a_h, 2048,
                                                        b_Wa, nullptr, att1_h, 512, 2048, 1);
  // featW = features @ W_ih[:,E:]^T        [3136,2048] K=2048 -> f16 g-interleaved
  k_gemm<<<dim3(2048 / 64, 3136 / 64), blk, 0, stream>>>(feat_h, 2048, W_ih_h + 512, 2560,
                                                         nullptr, nullptr, featW4, 0, 2048, 2);
  // gates_x = embed @ W_ih[:,:E]^T + b_ih + b_hh   [2048,2048] K=512 -> f32
  k_gemm<<<dim3(2048 / 64, 2048 / 64), blk, 0, stream>>>(Aemb, 512, W_ih_h, 2560,
                                                         b_ih, b_hh, gates_x, 2048, 512, 0);
  // Phase B: sequential recurrence (one block per batch element)
  k_seq<<<64, 512, 0, stream>>>(UaPK, b_Ua, att1_h, v_a, featW4, gates_x, Whh4, h0, c0,
                                Hbuf, out_attw);
  // Phase C: logits = H @ fc_W^T + fc_b    [2048,32000] K=512 -> f32 to d_out
  k_gemm<<<dim3(32000 / 64, 2048 / 64), blk, 0, stream>>>(Hbuf, 512, fc_W_h, 512,
                                                          fc_b, nullptr, out_logits, 32000, 512, 0);
}

// Round 2
// 1301.031 us; speedup vs baseline: 1.3939x; 1.3939x over previous
//
#include <hip/hip_runtime.h>
#include <hip/hip_fp16.h>

typedef _Float16 f16;
typedef _Float16 f16x2 __attribute__((ext_vector_type(2)));
typedef _Float16 f16x4 __attribute__((ext_vector_type(4)));
typedef _Float16 f16x8 __attribute__((ext_vector_type(8)));
typedef float    f32x4 __attribute__((ext_vector_type(4)));

// Problem constants: B=64, S=32, P=49, F=2048, E=512, H=512, V=32000

// ---------------- f32 -> f16 convert (vectorized) ----------------
__global__ void k_cvt(const float* __restrict__ in, f16* __restrict__ out, long n4) {
  long i = (long)blockIdx.x * blockDim.x + threadIdx.x;
  long stride = (long)gridDim.x * blockDim.x;
  for (; i < n4; i += stride) {
    float4 v = ((const float4*)in)[i];
    f16x4 o;
    o.x = (f16)v.x; o.y = (f16)v.y; o.z = (f16)v.z; o.w = (f16)v.w;
    ((f16x4*)out)[i] = o;
  }
}

// ---------------- embedding gather -> f16 A matrix (n = b*32+s) ----------------
__global__ void k_embed(const int* __restrict__ caps, const float* __restrict__ table,
                        f16* __restrict__ out) {
  int n = blockIdx.x;                 // 0..2047
  int tok = caps[n];
  const float* src = table + (long)tok * 512;
  f16* dst = out + (long)n * 512;
  for (int e = threadIdx.x; e < 512; e += 256) dst[e] = (f16)src[e];
}

// ---------------- mean features -> h16 (f16), c_state (f32) ----------------
__global__ __launch_bounds__(512) void k_h0c0(const float* __restrict__ feat,
                                              const float* __restrict__ Wh, const float* __restrict__ bh,
                                              const float* __restrict__ Wc, const float* __restrict__ bc,
                                              f16* __restrict__ h16, float* __restrict__ c_state) {
  __shared__ float mf[2048];
  int b = blockIdx.x, tid = threadIdx.x;
  for (int e = tid; e < 2048; e += 512) {
    float s = 0.f;
    for (int p = 0; p < 49; ++p) s += feat[((long)(b * 49 + p)) * 2048 + e];
    mf[e] = s * (1.f / 49.f);
  }
  __syncthreads();
  int j = tid;
  float ah = bh[j], ac = bc[j];
  const float4* whr = (const float4*)(Wh + (long)j * 2048);
  const float4* wcr = (const float4*)(Wc + (long)j * 2048);
  for (int e4 = 0; e4 < 512; ++e4) {
    float4 m4 = *(const float4*)&mf[e4 * 4];
    float4 a = whr[e4], cc = wcr[e4];
    ah += m4.x * a.x + m4.y * a.y + m4.z * a.z + m4.w * a.w;
    ac += m4.x * cc.x + m4.y * cc.y + m4.z * cc.z + m4.w * cc.w;
  }
  h16[(long)b * 512 + j] = (f16)ah;
  c_state[(long)b * 512 + j] = ac;
}

// ---------------- generic f16 MFMA GEMM: C[M,N] = A[M,K] @ W[N,K]^T + bias ----------------
// mode 0: f32 out @ ldc ; mode 1: f16 out @ ldc ; mode 2: f16 out g-interleaved (featW4)
__global__ __launch_bounds__(256) void k_gemm(const f16* __restrict__ A, long lda,
                                              const f16* __restrict__ Bw, long ldb,
                                              const float* __restrict__ bias1,
                                              const float* __restrict__ bias2,
                                              void* __restrict__ Cout, long ldc,
                                              int K, int mode) {
  __shared__ f16 As[64][40];   // +8 pad: bank-conflict-friendly b128 reads
  __shared__ f16 Bs[64][40];
  const int tid = threadIdx.x;
  const int lane = tid & 63, wave = tid >> 6;
  const long m0 = (long)blockIdx.y * 64, n0 = (long)blockIdx.x * 64;
  const int lr = tid >> 2, lc = (tid & 3) * 8;
  const int wr = (wave >> 1) * 32, wc = (wave & 1) * 32;
  f32x4 acc[2][2] = {};
  const f16* Ap = A + (m0 + lr) * lda + lc;
  const f16* Bp = Bw + (n0 + lr) * ldb + lc;
  for (int k0 = 0; k0 < K; k0 += 32) {
    uint4 av = *(const uint4*)(Ap + k0);
    uint4 bv = *(const uint4*)(Bp + k0);
    __syncthreads();
    *(uint4*)&As[lr][lc] = av;
    *(uint4*)&Bs[lr][lc] = bv;
    __syncthreads();
#pragma unroll
    for (int mi = 0; mi < 2; ++mi) {
      f16x8 af = *(const f16x8*)&As[wr + mi * 16 + (lane & 15)][(lane >> 4) * 8];
#pragma unroll
      for (int ni = 0; ni < 2; ++ni) {
        f16x8 bf = *(const f16x8*)&Bs[wc + ni * 16 + (lane & 15)][(lane >> 4) * 8];
        acc[mi][ni] = __builtin_amdgcn_mfma_f32_16x16x32_f16(af, bf, acc[mi][ni], 0, 0, 0);
      }
    }
  }
#pragma unroll
  for (int mi = 0; mi < 2; ++mi)
#pragma unroll
    for (int ni = 0; ni < 2; ++ni) {
      int row_b = wr + mi * 16 + (lane >> 4) * 4;
      long gcol = n0 + wc + ni * 16 + (lane & 15);
      float badd = (bias1 ? bias1[gcol] : 0.f) + (bias2 ? bias2[gcol] : 0.f);
#pragma unroll
      for (int r = 0; r < 4; ++r) {
        long grow = m0 + row_b + r;
        float v = acc[mi][ni][r] + badd;
        if (mode == 0)      ((float*)Cout)[grow * ldc + gcol] = v;
        else if (mode == 1) ((f16*)Cout)[grow * ldc + gcol] = (f16)v;
        else                ((f16*)Cout)[grow * 2048 + ((gcol & 511) << 2) + (gcol >> 9)] = (f16)v;
      }
    }
}

// ---------------- per-step: attention + softmax + ctx + LSTM pointwise ----------------
// R[b, 0:2048]   = h @ W_hh^T   (raw)
// R[b, 2048:2560] = h @ U_a^T   (raw)
__global__ __launch_bounds__(512) void k_step(const float* __restrict__ R,
                                              const float* __restrict__ b_Ua,
                                              const f16* __restrict__ att1,
                                              const float* __restrict__ va,
                                              const f16* __restrict__ featW4,
                                              const float* __restrict__ gates_x,
                                              float* __restrict__ c_state,
                                              f16* __restrict__ h16,
                                              f16* __restrict__ Hbuf,
                                              float* __restrict__ attw_out,
                                              int t) {
  __shared__ float att2[512];
  __shared__ float sc[64];
  __shared__ float wl[49];
  const int b = blockIdx.x, tid = threadIdx.x;
  const int lane = tid & 63, wave = tid >> 6;
  const long n = (long)b * 32 + t;
  const float* Rb = R + (long)b * 2560;

  att2[tid] = Rb[2048 + tid] + b_Ua[tid];
  __syncthreads();

  // scores: wave w handles p = w, w+8, ...
  for (int p = wave; p < 49; p += 8) {
    const f16* arow = att1 + ((long)b * 49 + p) * 512;
    float s = 0.f;
#pragma unroll
    for (int kk = 0; kk < 8; ++kk) {
      int k = lane + kk * 64;
      float x = (float)arow[k] + att2[k];
      float e = __expf(2.f * x);
      float th = 1.f - 2.f / (e + 1.f);
      s += va[k] * th;
    }
#pragma unroll
    for (int off = 32; off; off >>= 1) s += __shfl_xor(s, off);
    if (lane == 0) sc[p] = s;
  }
  __syncthreads();

  // softmax over P=49 by wave 0 (b_va is a constant shift -> softmax-invariant)
  if (wave == 0) {
    float s = (lane < 49) ? sc[lane] : -1e30f;
    float m = s;
#pragma unroll
    for (int off = 32; off; off >>= 1) m = fmaxf(m, __shfl_xor(m, off));
    float e = (lane < 49) ? __expf(s - m) : 0.f;
    float sum = e;
#pragma unroll
    for (int off = 32; off; off >>= 1) sum += __shfl_xor(sum, off);
    float wv = e / sum;
    if (lane < 49) { wl[lane] = wv; attw_out[n * 49 + lane] = wv; }
  }
  __syncthreads();

  // gates: col set {tid, 512+tid, 1024+tid, 1536+tid} = (i,f,g,o)[tid]
  const float* gx = gates_x + n * 2048;
  float g0 = gx[tid] + Rb[tid];
  float g1 = gx[512 + tid] + Rb[512 + tid];
  float g2 = gx[1024 + tid] + Rb[1024 + tid];
  float g3 = gx[1536 + tid] + Rb[1536 + tid];
  const f16* fwbase = featW4 + (long)b * 49 * 2048 + tid * 4;
#pragma unroll 7
  for (int p = 0; p < 49; ++p) {
    float wp = wl[p];
    uint2 u = *(const uint2*)(fwbase + (long)p * 2048);
    f16x2 aa = __builtin_bit_cast(f16x2, u.x);
    f16x2 bb = __builtin_bit_cast(f16x2, u.y);
    g0 += wp * (float)aa.x; g1 += wp * (float)aa.y;
    g2 += wp * (float)bb.x; g3 += wp * (float)bb.y;
  }
  // LSTM pointwise
  float c = c_state[(long)b * 512 + tid];
  float iv = 1.f / (1.f + __expf(-g0));
  float fv = 1.f / (1.f + __expf(-g1));
  float e2 = __expf(2.f * g2); float gv = 1.f - 2.f / (e2 + 1.f);
  float ov = 1.f / (1.f + __expf(-g3));
  c = fv * c + iv * gv;
  float e3 = __expf(2.f * c); float tc = 1.f - 2.f / (e3 + 1.f);
  float hn = ov * tc;
  c_state[(long)b * 512 + tid] = c;
  h16[(long)b * 512 + tid] = (f16)hn;
  Hbuf[n * 512 + tid] = (f16)hn;
}

extern "C" void kernel_launch(void* const* d_in, const int* in_sizes, int n_in,
                              void* d_out, int out_size, void* d_ws, size_t ws_size,
                              hipStream_t stream) {
  const int*   caps = (const int*)d_in[0];
  const float* feat = (const float*)d_in[1];
  const float* etab = (const float*)d_in[2];
  const float* W_a  = (const float*)d_in[3];
  const float* b_Wa = (const float*)d_in[4];
  const float* U_a  = (const float*)d_in[5];
  const float* b_Ua = (const float*)d_in[6];
  const float* v_a  = (const float*)d_in[7];
  /* d_in[8] b_va: softmax-invariant, unused */
  const float* W_ih = (const float*)d_in[9];
  const float* b_ih = (const float*)d_in[10];
  const float* W_hh = (const float*)d_in[11];
  const float* b_hh = (const float*)d_in[12];
  const float* fc_W = (const float*)d_in[13];
  const float* fc_b = (const float*)d_in[14];
  const float* Wh   = (const float*)d_in[15];
  const float* bh   = (const float*)d_in[16];
  const float* Wc   = (const float*)d_in[17];
  const float* bc   = (const float*)d_in[18];

  char* ws = (char*)d_ws;
  size_t off = 0;
  auto alloc = [&](size_t bytes) { void* p = ws + off; off += (bytes + 255) & ~(size_t)255; return p; };
  f16* feat_h  = (f16*)alloc(6422528ull * 2);   // B*P*F
  f16* W_a_h   = (f16*)alloc(1048576ull * 2);   // H*F
  f16* W_ih_h  = (f16*)alloc(5242880ull * 2);   // 4H*(E+F)
  f16* fc_W_h  = (f16*)alloc(16384000ull * 2);  // V*H
  f16* Aemb    = (f16*)alloc(1048576ull * 2);   // B*S*E
  f16* Wcat_h  = (f16*)alloc(1310720ull * 2);   // [W_hh;U_a] = [2560,512] f16
  f16* att1_h  = (f16*)alloc(1605632ull * 2);   // B*P*H
  f16* featW4  = (f16*)alloc(6422528ull * 2);   // B*P*4H interleaved
  float* gates_x = (float*)alloc(4194304ull * 4); // B*S*4H
  float* R     = (float*)alloc(163840ull * 4);  // [64,2560] per-step GEMM out
  f16* h16     = (f16*)alloc(32768ull * 2);     // [64,512] h state
  float* c_state = (float*)alloc(32768ull * 4); // [64,512] c state
  f16* Hbuf    = (f16*)alloc(1048576ull * 2);   // B*S*H
  (void)ws_size; (void)in_sizes; (void)n_in; (void)out_size;

  float* out_logits = (float*)d_out;
  float* out_attw   = out_logits + 65536000ull;

  // Phase A: converts / packs / precompute
  k_cvt<<<2048, 256, 0, stream>>>(feat, feat_h, 6422528 / 4);
  k_cvt<<<1024, 256, 0, stream>>>(W_a, W_a_h, 1048576 / 4);
  k_cvt<<<2048, 256, 0, stream>>>(W_ih, W_ih_h, 5242880 / 4);
  k_cvt<<<4096, 256, 0, stream>>>(fc_W, fc_W_h, 16384000 / 4);
  k_cvt<<<1024, 256, 0, stream>>>(W_hh, Wcat_h, 1048576 / 4);            // rows 0..2047
  k_cvt<<<256, 256, 0, stream>>>(U_a, Wcat_h + 2048ull * 512, 262144 / 4); // rows 2048..2559
  k_embed<<<2048, 256, 0, stream>>>(caps, etab, Aemb);
  k_h0c0<<<64, 512, 0, stream>>>(feat, Wh, bh, Wc, bc, h16, c_state);

  dim3 blk(256);
  // att1 = features @ W_a^T + b_Wa         [3136,512]  K=2048 -> f16
  k_gemm<<<dim3(512 / 64, 3136 / 64), blk, 0, stream>>>(feat_h, 2048, W_a_h, 2048,
                                                        b_Wa, nullptr, att1_h, 512, 2048, 1);
  // featW = features @ W_ih[:,E:]^T        [3136,2048] K=2048 -> f16 g-interleaved
  k_gemm<<<dim3(2048 / 64, 3136 / 64), blk, 0, stream>>>(feat_h, 2048, W_ih_h + 512, 2560,
                                                         nullptr, nullptr, featW4, 0, 2048, 2);
  // gates_x = embed @ W_ih[:,:E]^T + b_ih + b_hh   [2048,2048] K=512 -> f32
  k_gemm<<<dim3(2048 / 64, 2048 / 64), blk, 0, stream>>>(Aemb, 512, W_ih_h, 2560,
                                                         b_ih, b_hh, gates_x, 2048, 512, 0);

  // Phase B: sequential recurrence — per step: batched [W_hh;U_a] GEMM, then pointwise
  for (int t = 0; t < 32; ++t) {
    // R = h16 @ Wcat^T   [64, 2560] K=512 (raw f32)
    k_gemm<<<dim3(2560 / 64, 1), blk, 0, stream>>>(h16, 512, Wcat_h, 512,
                                                   nullptr, nullptr, R, 2560, 512, 0);
    k_step<<<64, 512, 0, stream>>>(R, b_Ua, att1_h, v_a, featW4, gates_x,
                                   c_state, h16, Hbuf, out_attw, t);
  }

  // Phase C: logits = H @ fc_W^T + fc_b    [2048,32000] K=512 -> f32 to d_out
  k_gemm<<<dim3(32000 / 64, 2048 / 64), blk, 0, stream>>>(Hbuf, 512, fc_W_h, 512,
                                                          fc_b, nullptr, out_logits, 32000, 512, 0);
}

// Round 3
// 1091.891 us; speedup vs baseline: 1.6609x; 1.1915x over previous
//
#include <hip/hip_runtime.h>
#include <hip/hip_fp16.h>

typedef _Float16 f16;
typedef _Float16 f16x2 __attribute__((ext_vector_type(2)));
typedef _Float16 f16x4 __attribute__((ext_vector_type(4)));
typedef _Float16 f16x8 __attribute__((ext_vector_type(8)));
typedef float    f32x4 __attribute__((ext_vector_type(4)));

// Problem constants: B=64, S=32, P=49, F=2048, E=512, H=512, V=32000

// ---------------- f32 -> f16 convert (vectorized) ----------------
__global__ void k_cvt(const float* __restrict__ in, f16* __restrict__ out, long n4) {
  long i = (long)blockIdx.x * blockDim.x + threadIdx.x;
  long stride = (long)gridDim.x * blockDim.x;
  for (; i < n4; i += stride) {
    float4 v = ((const float4*)in)[i];
    f16x4 o;
    o.x = (f16)v.x; o.y = (f16)v.y; o.z = (f16)v.z; o.w = (f16)v.w;
    ((f16x4*)out)[i] = o;
  }
}

// ---------------- embedding gather -> f16 A matrix (n = b*32+s) ----------------
__global__ void k_embed(const int* __restrict__ caps, const float* __restrict__ table,
                        f16* __restrict__ out) {
  int n = blockIdx.x;                 // 0..2047
  int tok = caps[n];
  const float* src = table + (long)tok * 512;
  f16* dst = out + (long)n * 512;
  for (int e = threadIdx.x; e < 512; e += 256) dst[e] = (f16)src[e];
}

// ---------------- mean of features over P (from f16 feat) -> f16 [64,2048] ----------------
__global__ __launch_bounds__(256) void k_mean(const f16* __restrict__ feat_h,
                                              f16* __restrict__ mean_h) {
  int b = blockIdx.x;
  int e4 = blockIdx.y * 256 + threadIdx.x;      // f16x4 index within row: 0..511
  const f16x4* src = (const f16x4*)(feat_h + (long)b * 49 * 2048) + e4;
  float s0 = 0.f, s1 = 0.f, s2 = 0.f, s3 = 0.f;
#pragma unroll 7
  for (int p = 0; p < 49; ++p) {
    f16x4 v = src[p * 512];
    s0 += (float)v.x; s1 += (float)v.y; s2 += (float)v.z; s3 += (float)v.w;
  }
  const float inv = 1.f / 49.f;
  f16x4 o; o.x = (f16)(s0 * inv); o.y = (f16)(s1 * inv); o.z = (f16)(s2 * inv); o.w = (f16)(s3 * inv);
  ((f16x4*)(mean_h + (long)b * 2048))[e4] = o;
}

// ---------------- split h0/c0 GEMM result, add biases ----------------
__global__ __launch_bounds__(512) void k_h0split(const float* __restrict__ Rh0,
                                                 const float* __restrict__ bh,
                                                 const float* __restrict__ bc,
                                                 f16* __restrict__ h16,
                                                 float* __restrict__ c_state) {
  int b = blockIdx.x, j = threadIdx.x;
  h16[(long)b * 512 + j] = (f16)(Rh0[(long)b * 1024 + j] + bh[j]);
  c_state[(long)b * 512 + j] = Rh0[(long)b * 1024 + 512 + j] + bc[j];
}

// ---------------- generic f16 MFMA GEMM: C[M,N] = A[M,K] @ W[N,K]^T + bias ----------------
// mode 0: f32 out @ ldc ; mode 1: f16 out @ ldc ; mode 2: f16 out g-interleaved (featW4)
__global__ __launch_bounds__(256) void k_gemm(const f16* __restrict__ A, long lda,
                                              const f16* __restrict__ Bw, long ldb,
                                              const float* __restrict__ bias1,
                                              const float* __restrict__ bias2,
                                              void* __restrict__ Cout, long ldc,
                                              int K, int mode) {
  __shared__ f16 As[64][40];   // +8 pad: bank-conflict-friendly b128 reads
  __shared__ f16 Bs[64][40];
  const int tid = threadIdx.x;
  const int lane = tid & 63, wave = tid >> 6;
  const long m0 = (long)blockIdx.y * 64, n0 = (long)blockIdx.x * 64;
  const int lr = tid >> 2, lc = (tid & 3) * 8;
  const int wr = (wave >> 1) * 32, wc = (wave & 1) * 32;
  f32x4 acc[2][2] = {};
  const f16* Ap = A + (m0 + lr) * lda + lc;
  const f16* Bp = Bw + (n0 + lr) * ldb + lc;
  for (int k0 = 0; k0 < K; k0 += 32) {
    uint4 av = *(const uint4*)(Ap + k0);
    uint4 bv = *(const uint4*)(Bp + k0);
    __syncthreads();
    *(uint4*)&As[lr][lc] = av;
    *(uint4*)&Bs[lr][lc] = bv;
    __syncthreads();
#pragma unroll
    for (int mi = 0; mi < 2; ++mi) {
      f16x8 af = *(const f16x8*)&As[wr + mi * 16 + (lane & 15)][(lane >> 4) * 8];
#pragma unroll
      for (int ni = 0; ni < 2; ++ni) {
        f16x8 bf = *(const f16x8*)&Bs[wc + ni * 16 + (lane & 15)][(lane >> 4) * 8];
        acc[mi][ni] = __builtin_amdgcn_mfma_f32_16x16x32_f16(af, bf, acc[mi][ni], 0, 0, 0);
      }
    }
  }
#pragma unroll
  for (int mi = 0; mi < 2; ++mi)
#pragma unroll
    for (int ni = 0; ni < 2; ++ni) {
      int row_b = wr + mi * 16 + (lane >> 4) * 4;
      long gcol = n0 + wc + ni * 16 + (lane & 15);
      float badd = (bias1 ? bias1[gcol] : 0.f) + (bias2 ? bias2[gcol] : 0.f);
#pragma unroll
      for (int r = 0; r < 4; ++r) {
        long grow = m0 + row_b + r;
        float v = acc[mi][ni][r] + badd;
        if (mode == 0)      ((float*)Cout)[grow * ldc + gcol] = v;
        else if (mode == 1) ((f16*)Cout)[grow * ldc + gcol] = (f16)v;
        else                ((f16*)Cout)[grow * 2048 + ((gcol & 511) << 2) + (gcol >> 9)] = (f16)v;
      }
    }
}

// ---------------- per-step: attention + softmax + ctx + LSTM pointwise ----------------
// R[b, 0:2048]   = h @ W_hh^T   (raw)
// R[b, 2048:2560] = h @ U_a^T   (raw)
__global__ __launch_bounds__(512) void k_step(const float* __restrict__ R,
                                              const float* __restrict__ b_Ua,
                                              const f16* __restrict__ att1,
                                              const float* __restrict__ va,
                                              const f16* __restrict__ featW4,
                                              const float* __restrict__ gates_x,
                                              float* __restrict__ c_state,
                                              f16* __restrict__ h16,
                                              f16* __restrict__ Hbuf,
                                              float* __restrict__ attw_out,
                                              int t) {
  __shared__ float att2[512];
  __shared__ float sc[64];
  __shared__ float wl[49];
  const int b = blockIdx.x, tid = threadIdx.x;
  const int lane = tid & 63, wave = tid >> 6;
  const long n = (long)b * 32 + t;
  const float* Rb = R + (long)b * 2560;

  att2[tid] = Rb[2048 + tid] + b_Ua[tid];
  __syncthreads();

  // scores: wave w handles p = w, w+8, ...
  for (int p = wave; p < 49; p += 8) {
    const f16* arow = att1 + ((long)b * 49 + p) * 512;
    float s = 0.f;
#pragma unroll
    for (int kk = 0; kk < 8; ++kk) {
      int k = lane + kk * 64;
      float x = (float)arow[k] + att2[k];
      float e = __expf(2.f * x);
      float th = 1.f - 2.f / (e + 1.f);
      s += va[k] * th;
    }
#pragma unroll
    for (int off = 32; off; off >>= 1) s += __shfl_xor(s, off);
    if (lane == 0) sc[p] = s;
  }
  __syncthreads();

  // softmax over P=49 by wave 0 (b_va is a constant shift -> softmax-invariant)
  if (wave == 0) {
    float s = (lane < 49) ? sc[lane] : -1e30f;
    float m = s;
#pragma unroll
    for (int off = 32; off; off >>= 1) m = fmaxf(m, __shfl_xor(m, off));
    float e = (lane < 49) ? __expf(s - m) : 0.f;
    float sum = e;
#pragma unroll
    for (int off = 32; off; off >>= 1) sum += __shfl_xor(sum, off);
    float wv = e / sum;
    if (lane < 49) { wl[lane] = wv; attw_out[n * 49 + lane] = wv; }
  }
  __syncthreads();

  // gates: col set {tid, 512+tid, 1024+tid, 1536+tid} = (i,f,g,o)[tid]
  const float* gx = gates_x + n * 2048;
  float g0 = gx[tid] + Rb[tid];
  float g1 = gx[512 + tid] + Rb[512 + tid];
  float g2 = gx[1024 + tid] + Rb[1024 + tid];
  float g3 = gx[1536 + tid] + Rb[1536 + tid];
  const f16* fwbase = featW4 + (long)b * 49 * 2048 + tid * 4;
#pragma unroll 7
  for (int p = 0; p < 49; ++p) {
    float wp = wl[p];
    uint2 u = *(const uint2*)(fwbase + (long)p * 2048);
    f16x2 aa = __builtin_bit_cast(f16x2, u.x);
    f16x2 bb = __builtin_bit_cast(f16x2, u.y);
    g0 += wp * (float)aa.x; g1 += wp * (float)aa.y;
    g2 += wp * (float)bb.x; g3 += wp * (float)bb.y;
  }
  // LSTM pointwise
  float c = c_state[(long)b * 512 + tid];
  float iv = 1.f / (1.f + __expf(-g0));
  float fv = 1.f / (1.f + __expf(-g1));
  float e2 = __expf(2.f * g2); float gv = 1.f - 2.f / (e2 + 1.f);
  float ov = 1.f / (1.f + __expf(-g3));
  c = fv * c + iv * gv;
  float e3 = __expf(2.f * c); float tc = 1.f - 2.f / (e3 + 1.f);
  float hn = ov * tc;
  c_state[(long)b * 512 + tid] = c;
  h16[(long)b * 512 + tid] = (f16)hn;
  Hbuf[n * 512 + tid] = (f16)hn;
}

extern "C" void kernel_launch(void* const* d_in, const int* in_sizes, int n_in,
                              void* d_out, int out_size, void* d_ws, size_t ws_size,
                              hipStream_t stream) {
  const int*   caps = (const int*)d_in[0];
  const float* feat = (const float*)d_in[1];
  const float* etab = (const float*)d_in[2];
  const float* W_a  = (const float*)d_in[3];
  const float* b_Wa = (const float*)d_in[4];
  const float* U_a  = (const float*)d_in[5];
  const float* b_Ua = (const float*)d_in[6];
  const float* v_a  = (const float*)d_in[7];
  /* d_in[8] b_va: softmax-invariant, unused */
  const float* W_ih = (const float*)d_in[9];
  const float* b_ih = (const float*)d_in[10];
  const float* W_hh = (const float*)d_in[11];
  const float* b_hh = (const float*)d_in[12];
  const float* fc_W = (const float*)d_in[13];
  const float* fc_b = (const float*)d_in[14];
  const float* Wh   = (const float*)d_in[15];
  const float* bh   = (const float*)d_in[16];
  const float* Wc   = (const float*)d_in[17];
  const float* bc   = (const float*)d_in[18];

  char* ws = (char*)d_ws;
  size_t off = 0;
  auto alloc = [&](size_t bytes) { void* p = ws + off; off += (bytes + 255) & ~(size_t)255; return p; };
  f16* feat_h  = (f16*)alloc(6422528ull * 2);   // B*P*F
  f16* W_a_h   = (f16*)alloc(1048576ull * 2);   // H*F
  f16* W_ih_h  = (f16*)alloc(5242880ull * 2);   // 4H*(E+F)
  f16* fc_W_h  = (f16*)alloc(16384000ull * 2);  // V*H
  f16* Aemb    = (f16*)alloc(1048576ull * 2);   // B*S*E
  f16* Wcat_h  = (f16*)alloc(1310720ull * 2);   // [W_hh;U_a] = [2560,512] f16
  f16* Whc_h   = (f16*)alloc(2097152ull * 2);   // [Wh;Wc] = [1024,2048] f16
  f16* mean_h  = (f16*)alloc(131072ull * 2);    // [64,2048] mean features f16
  f16* att1_h  = (f16*)alloc(1605632ull * 2);   // B*P*H
  f16* featW4  = (f16*)alloc(6422528ull * 2);   // B*P*4H interleaved
  float* gates_x = (float*)alloc(4194304ull * 4); // B*S*4H
  float* R     = (float*)alloc(163840ull * 4);  // [64,2560] per-step GEMM out (also h0/c0 GEMM out)
  f16* h16     = (f16*)alloc(32768ull * 2);     // [64,512] h state
  float* c_state = (float*)alloc(32768ull * 4); // [64,512] c state
  f16* Hbuf    = (f16*)alloc(1048576ull * 2);   // B*S*H
  (void)ws_size; (void)in_sizes; (void)n_in; (void)out_size;

  float* out_logits = (float*)d_out;
  float* out_attw   = out_logits + 65536000ull;

  // Phase A: converts / packs / precompute
  k_cvt<<<2048, 256, 0, stream>>>(feat, feat_h, 6422528 / 4);
  k_cvt<<<1024, 256, 0, stream>>>(W_a, W_a_h, 1048576 / 4);
  k_cvt<<<2048, 256, 0, stream>>>(W_ih, W_ih_h, 5242880 / 4);
  k_cvt<<<4096, 256, 0, stream>>>(fc_W, fc_W_h, 16384000 / 4);
  k_cvt<<<1024, 256, 0, stream>>>(W_hh, Wcat_h, 1048576 / 4);              // rows 0..2047
  k_cvt<<<256, 256, 0, stream>>>(U_a, Wcat_h + 2048ull * 512, 262144 / 4); // rows 2048..2559
  k_cvt<<<512, 256, 0, stream>>>(Wh, Whc_h, 1048576 / 4);                  // rows 0..511
  k_cvt<<<512, 256, 0, stream>>>(Wc, Whc_h + 1048576ull, 1048576 / 4);     // rows 512..1023
  k_embed<<<2048, 256, 0, stream>>>(caps, etab, Aemb);
  k_mean<<<dim3(64, 2), 256, 0, stream>>>(feat_h, mean_h);

  dim3 blk(256);
  // h0/c0: [64,1024] = mean_h @ [Wh;Wc]^T  K=2048 -> f32 (biases added in split)
  k_gemm<<<dim3(1024 / 64, 1), blk, 0, stream>>>(mean_h, 2048, Whc_h, 2048,
                                                 nullptr, nullptr, R, 1024, 2048, 0);
  k_h0split<<<64, 512, 0, stream>>>(R, bh, bc, h16, c_state);

  // att1 = features @ W_a^T + b_Wa         [3136,512]  K=2048 -> f16
  k_gemm<<<dim3(512 / 64, 3136 / 64), blk, 0, stream>>>(feat_h, 2048, W_a_h, 2048,
                                                        b_Wa, nullptr, att1_h, 512, 2048, 1);
  // featW = features @ W_ih[:,E:]^T        [3136,2048] K=2048 -> f16 g-interleaved
  k_gemm<<<dim3(2048 / 64, 3136 / 64), blk, 0, stream>>>(feat_h, 2048, W_ih_h + 512, 2560,
                                                         nullptr, nullptr, featW4, 0, 2048, 2);
  // gates_x = embed @ W_ih[:,:E]^T + b_ih + b_hh   [2048,2048] K=512 -> f32
  k_gemm<<<dim3(2048 / 64, 2048 / 64), blk, 0, stream>>>(Aemb, 512, W_ih_h, 2560,
                                                         b_ih, b_hh, gates_x, 2048, 512, 0);

  // Phase B: sequential recurrence — per step: batched [W_hh;U_a] GEMM, then pointwise
  for (int t = 0; t < 32; ++t) {
    // R = h16 @ Wcat^T   [64, 2560] K=512 (raw f32)
    k_gemm<<<dim3(2560 / 64, 1), blk, 0, stream>>>(h16, 512, Wcat_h, 512,
                                                   nullptr, nullptr, R, 2560, 512, 0);
    k_step<<<64, 512, 0, stream>>>(R, b_Ua, att1_h, v_a, featW4, gates_x,
                                   c_state, h16, Hbuf, out_attw, t);
  }

  // Phase C: logits = H @ fc_W^T + fc_b    [2048,32000] K=512 -> f32 to d_out
  k_gemm<<<dim3(32000 / 64, 2048 / 64), blk, 0, stream>>>(Hbuf, 512, fc_W_h, 512,
                                                          fc_b, nullptr, out_logits, 32000, 512, 0);
}